// Round 1
// baseline (606.844 us; speedup 1.0000x reference)
//
#include <hip/hip_runtime.h>
#include <hip/hip_bf16.h>

#define BB 8
#define NN 2048
#define DD 128
#define NSTEPS 16
#define DT_F 0.1f
#define TWO_PI_F 6.283185307179586f

typedef short short8 __attribute__((ext_vector_type(8)));
typedef float floatx4 __attribute__((ext_vector_type(4)));

// ---------------- K0: split fp32 embeddings into bf16 hi/lo ----------------
__global__ void split_kernel(const float* __restrict__ e,
                             __hip_bfloat16* __restrict__ hi,
                             __hip_bfloat16* __restrict__ lo) {
    int i = blockIdx.x * 256 + threadIdx.x;
    float x = e[i];
    __hip_bfloat16 h = __float2bfloat16(x);
    hi[i] = h;
    lo[i] = __float2bfloat16(x - __bfloat162float(h));
}

// ---------------- K1: coupling matrix via bf16 MFMA (hi/lo split) ----------
// 64x64 output tile per block (256 thr = 4 waves), K = 128.
#define LDP 136  // padded LDS row stride in bf16 elems (136*2B=272B -> 2-way bank alias only)

__launch_bounds__(256, 2)
__global__ void coupling_kernel(const __hip_bfloat16* __restrict__ Ehi,
                                const __hip_bfloat16* __restrict__ Elo,
                                __hip_bfloat16* __restrict__ C) {
    __shared__ __hip_bfloat16 Ah[64 * LDP];
    __shared__ __hip_bfloat16 Al[64 * LDP];
    __shared__ __hip_bfloat16 Bh[64 * LDP];
    __shared__ __hip_bfloat16 Bl[64 * LDP];

    const int b  = blockIdx.z;
    const int n0 = blockIdx.y * 64;
    const int m0 = blockIdx.x * 64;
    const int tid = threadIdx.x;

    const __hip_bfloat16* aHsrc = Ehi + ((size_t)b * NN + n0) * DD;
    const __hip_bfloat16* aLsrc = Elo + ((size_t)b * NN + n0) * DD;
    const __hip_bfloat16* bHsrc = Ehi + ((size_t)b * NN + m0) * DD;
    const __hip_bfloat16* bLsrc = Elo + ((size_t)b * NN + m0) * DD;

    // stage 64x128 bf16 tiles (1024 uint4 chunks each, 4 per thread)
    #pragma unroll
    for (int i = 0; i < 4; ++i) {
        int c   = tid + 256 * i;
        int row = c >> 4;            // 16 x 16B chunks per 128-elem row
        int col = (c & 15) * 8;
        *(uint4*)(Ah + row * LDP + col) = *(const uint4*)(aHsrc + row * DD + col);
        *(uint4*)(Al + row * LDP + col) = *(const uint4*)(aLsrc + row * DD + col);
        *(uint4*)(Bh + row * LDP + col) = *(const uint4*)(bHsrc + row * DD + col);
        *(uint4*)(Bl + row * LDP + col) = *(const uint4*)(bLsrc + row * DD + col);
    }
    __syncthreads();

    const int wave = tid >> 6;
    const int lane = tid & 63;
    const int l16  = lane & 15;
    const int quad = lane >> 4;

    floatx4 acc[4] = {floatx4{0,0,0,0}, floatx4{0,0,0,0},
                      floatx4{0,0,0,0}, floatx4{0,0,0,0}};

    const int arow = wave * 16 + l16;
    #pragma unroll
    for (int kt = 0; kt < 4; ++kt) {
        const int ko = kt * 32 + quad * 8;
        short8 ah = *(const short8*)(Ah + arow * LDP + ko);
        short8 al = *(const short8*)(Al + arow * LDP + ko);
        #pragma unroll
        for (int c = 0; c < 4; ++c) {
            const int brow = c * 16 + l16;
            short8 bh = *(const short8*)(Bh + brow * LDP + ko);
            short8 bl = *(const short8*)(Bl + brow * LDP + ko);
            acc[c] = __builtin_amdgcn_mfma_f32_16x16x32_bf16(ah, bh, acc[c], 0, 0, 0);
            acc[c] = __builtin_amdgcn_mfma_f32_16x16x32_bf16(ah, bl, acc[c], 0, 0, 0);
            acc[c] = __builtin_amdgcn_mfma_f32_16x16x32_bf16(al, bh, acc[c], 0, 0, 0);
        }
    }

    // epilogue: lorentz = G_full - 2*t_n*t_m ; arg = max(-lorentz, 1+1e-7)
    float tnv[4];
    #pragma unroll
    for (int i = 0; i < 4; ++i) {
        int r = wave * 16 + quad * 4 + i;
        tnv[i] = __bfloat162float(Ah[r * LDP]) + __bfloat162float(Al[r * LDP]);
    }
    #pragma unroll
    for (int c = 0; c < 4; ++c) {
        int br = c * 16 + l16;
        float tm = __bfloat162float(Bh[br * LDP]) + __bfloat162float(Bl[br * LDP]);
        size_t base = ((size_t)b * NN + n0 + wave * 16 + quad * 4) * (size_t)NN
                      + m0 + c * 16 + l16;
        #pragma unroll
        for (int i = 0; i < 4; ++i) {
            float g   = acc[c][i];
            float arg = fmaxf(2.0f * tnv[i] * tm - g, 1.0f + 1e-7f);
            float dL  = acoshf(arg);
            float cp  = __expf(-dL * (1.0f / 1.000001f));
            cp = fminf(fmaxf(cp, 0.0f), 1.0f);
            C[base + (size_t)i * NN] = __float2bfloat16(cp);
        }
    }
}

// ---------------- K2: one Kuramoto step -----------------------------------
// sum_m C[n,m] sin(tn - tm) = sin(tn) * (C.cos) - cos(tn) * (C.sin)
// block = 256 thr (4 waves), 16 rows/block; wave-per-row dots; cs in regs.
__launch_bounds__(256, 4)
__global__ void step_kernel(const __hip_bfloat16* __restrict__ C,
                            const float* __restrict__ theta_in,
                            float* __restrict__ theta_out,
                            const float* __restrict__ omega) {
    __shared__ float2 cs[NN];
    const int tid = threadIdx.x;
    const int b   = blockIdx.x >> 7;      // NN/16 = 128 row-blocks per batch
    const int rb  = blockIdx.x & 127;
    const float* th_b = theta_in + b * NN;

    #pragma unroll
    for (int i = 0; i < 8; ++i) {
        int m = tid * 8 + i;
        float th = th_b[m];
        float sv, cv;
        sincosf(th, &sv, &cv);
        cs[m] = make_float2(cv, sv);
    }
    __syncthreads();

    const int lane = tid & 63;
    const int wave = tid >> 6;

    float cc[32], ssr[32];
    #pragma unroll
    for (int j = 0; j < 4; ++j) {
        #pragma unroll
        for (int i = 0; i < 8; ++i) {
            float2 v = cs[j * 512 + lane * 8 + i];
            cc[j * 8 + i]  = v.x;
            ssr[j * 8 + i] = v.y;
        }
    }

    #pragma unroll 1
    for (int q = 0; q < 4; ++q) {
        const int n = rb * 16 + wave * 4 + q;
        const __hip_bfloat16* Crow = C + ((size_t)b * NN + n) * (size_t)NN;
        float a0 = 0.f, a1 = 0.f, s0 = 0.f, s1 = 0.f;
        #pragma unroll
        for (int j = 0; j < 4; ++j) {
            uint4 v = *(const uint4*)(Crow + j * 512 + lane * 8);
            unsigned u[4] = {v.x, v.y, v.z, v.w};
            #pragma unroll
            for (int k = 0; k < 4; ++k) {
                float f0 = __uint_as_float(u[k] << 16);
                float f1 = __uint_as_float(u[k] & 0xffff0000u);
                int idx = j * 8 + 2 * k;
                a0 = fmaf(f0, cc[idx],      a0);
                s0 = fmaf(f0, ssr[idx],     s0);
                a1 = fmaf(f1, cc[idx + 1],  a1);
                s1 = fmaf(f1, ssr[idx + 1], s1);
            }
        }
        float ac = a0 + a1;
        float as = s0 + s1;
        #pragma unroll
        for (int off = 32; off >= 1; off >>= 1) {
            ac += __shfl_xor(ac, off, 64);
            as += __shfl_xor(as, off, 64);
        }
        if (lane == 0) {
            float th = th_b[n];
            float sn, cn;
            sincosf(th, &sn, &cn);
            float sum = sn * ac - cn * as;
            float dth = omega[n] + (1.0f / NN) * sum;
            theta_out[b * NN + n] = fmodf(th + DT_F * dth, TWO_PI_F);
        }
    }
}

// ---------------- launch ----------------------------------------------------
extern "C" void kernel_launch(void* const* d_in, const int* in_sizes, int n_in,
                              void* d_out, int out_size, void* d_ws, size_t ws_size,
                              hipStream_t stream) {
    const float* theta0 = (const float*)d_in[0];
    const float* emb    = (const float*)d_in[1];
    const float* omega  = (const float*)d_in[2];
    float* out = (float*)d_out;

    char* ws = (char*)d_ws;
    __hip_bfloat16* C   = (__hip_bfloat16*)ws;                       // 64 MiB
    __hip_bfloat16* Ehi = (__hip_bfloat16*)(ws + 67108864);          // 4 MiB
    __hip_bfloat16* Elo = (__hip_bfloat16*)(ws + 71303168);          // 4 MiB
    float* tA = (float*)(ws + 75497472);                             // 64 KiB
    float* tB = (float*)(ws + 75563008);                             // 64 KiB

    split_kernel<<<(BB * NN * DD) / 256, 256, 0, stream>>>(emb, Ehi, Elo);

    dim3 g1(NN / 64, NN / 64, BB);
    coupling_kernel<<<g1, 256, 0, stream>>>(Ehi, Elo, C);

    const float* tin = theta0;
    for (int s = 0; s < NSTEPS; ++s) {
        float* tout = (s == NSTEPS - 1) ? out : ((s & 1) ? tB : tA);
        step_kernel<<<dim3(BB * (NN / 16)), 256, 0, stream>>>(C, tin, tout, omega);
        tin = tout;
    }
}

// Round 2
// 386.883 us; speedup vs baseline: 1.5685x; 1.5685x over previous
//
#include <hip/hip_runtime.h>
#include <hip/hip_bf16.h>

#define BB 8
#define NN 2048
#define DD 128
#define NSTEPS 16
#define DT_F 0.1f
#define TWO_PI_F 6.283185307179586f

typedef short short8 __attribute__((ext_vector_type(8)));
typedef float floatx4 __attribute__((ext_vector_type(4)));

// ---------------- K0: split fp32 embeddings into bf16 hi/lo ----------------
__global__ void split_kernel(const float* __restrict__ e,
                             __hip_bfloat16* __restrict__ hi,
                             __hip_bfloat16* __restrict__ lo) {
    int i = blockIdx.x * 256 + threadIdx.x;
    float x = e[i];
    __hip_bfloat16 h = __float2bfloat16(x);
    hi[i] = h;
    lo[i] = __float2bfloat16(x - __bfloat162float(h));
}

// ---------------- K1: coupling matrix via bf16 MFMA (hi/lo split) ----------
// 64x64 output tile per block (256 thr = 4 waves), K = 128.
// Epilogue identity: exp(-acosh(x)) = 1/(x + sqrt(x^2-1)); the /1.000001
// tau factor is a <=1e-5 relative correction, invisible in bf16 storage.
#define LDP 136  // padded LDS row stride in bf16 elems

__launch_bounds__(256, 2)
__global__ void coupling_kernel(const __hip_bfloat16* __restrict__ Ehi,
                                const __hip_bfloat16* __restrict__ Elo,
                                __hip_bfloat16* __restrict__ C) {
    __shared__ __hip_bfloat16 Ah[64 * LDP];
    __shared__ __hip_bfloat16 Al[64 * LDP];
    __shared__ __hip_bfloat16 Bh[64 * LDP];
    __shared__ __hip_bfloat16 Bl[64 * LDP];

    const int b  = blockIdx.z;
    const int n0 = blockIdx.y * 64;
    const int m0 = blockIdx.x * 64;
    const int tid = threadIdx.x;

    const __hip_bfloat16* aHsrc = Ehi + ((size_t)b * NN + n0) * DD;
    const __hip_bfloat16* aLsrc = Elo + ((size_t)b * NN + n0) * DD;
    const __hip_bfloat16* bHsrc = Ehi + ((size_t)b * NN + m0) * DD;
    const __hip_bfloat16* bLsrc = Elo + ((size_t)b * NN + m0) * DD;

    #pragma unroll
    for (int i = 0; i < 4; ++i) {
        int c   = tid + 256 * i;
        int row = c >> 4;
        int col = (c & 15) * 8;
        *(uint4*)(Ah + row * LDP + col) = *(const uint4*)(aHsrc + row * DD + col);
        *(uint4*)(Al + row * LDP + col) = *(const uint4*)(aLsrc + row * DD + col);
        *(uint4*)(Bh + row * LDP + col) = *(const uint4*)(bHsrc + row * DD + col);
        *(uint4*)(Bl + row * LDP + col) = *(const uint4*)(bLsrc + row * DD + col);
    }
    __syncthreads();

    const int wave = tid >> 6;
    const int lane = tid & 63;
    const int l16  = lane & 15;
    const int quad = lane >> 4;

    floatx4 acc[4] = {floatx4{0,0,0,0}, floatx4{0,0,0,0},
                      floatx4{0,0,0,0}, floatx4{0,0,0,0}};

    const int arow = wave * 16 + l16;
    #pragma unroll
    for (int kt = 0; kt < 4; ++kt) {
        const int ko = kt * 32 + quad * 8;
        short8 ah = *(const short8*)(Ah + arow * LDP + ko);
        short8 al = *(const short8*)(Al + arow * LDP + ko);
        #pragma unroll
        for (int c = 0; c < 4; ++c) {
            const int brow = c * 16 + l16;
            short8 bh = *(const short8*)(Bh + brow * LDP + ko);
            short8 bl = *(const short8*)(Bl + brow * LDP + ko);
            acc[c] = __builtin_amdgcn_mfma_f32_16x16x32_bf16(ah, bh, acc[c], 0, 0, 0);
            acc[c] = __builtin_amdgcn_mfma_f32_16x16x32_bf16(ah, bl, acc[c], 0, 0, 0);
            acc[c] = __builtin_amdgcn_mfma_f32_16x16x32_bf16(al, bh, acc[c], 0, 0, 0);
        }
    }

    float tn2[4];  // 2 * t_n
    #pragma unroll
    for (int i = 0; i < 4; ++i) {
        int r = wave * 16 + quad * 4 + i;
        tn2[i] = 2.0f * (__bfloat162float(Ah[r * LDP]) + __bfloat162float(Al[r * LDP]));
    }
    #pragma unroll
    for (int c = 0; c < 4; ++c) {
        int br = c * 16 + l16;
        float tm = __bfloat162float(Bh[br * LDP]) + __bfloat162float(Bl[br * LDP]);
        size_t base = ((size_t)b * NN + n0 + wave * 16 + quad * 4) * (size_t)NN
                      + m0 + c * 16 + l16;
        #pragma unroll
        for (int i = 0; i < 4; ++i) {
            float g   = acc[c][i];
            float arg = fmaxf(fmaf(tn2[i], tm, -g), 1.0f + 1e-7f);
            float s   = sqrtf(fmaf(arg, arg, -1.0f));       // fma: no cancellation
            float cp  = __builtin_amdgcn_rcpf(arg + s);      // = exp(-acosh(arg))
            C[base + (size_t)i * NN] = __float2bfloat16(fminf(cp, 1.0f));
        }
    }
}

// ---------------- K2: one Kuramoto step -----------------------------------
// sum_m C[n,m] sin(tn - tm) = sin(tn) * (C.cos) - cos(tn) * (C.sin)
// 16 rows/block; wave-per-4-rows; ALL 16 C-loads hoisted (latency overlap).
__launch_bounds__(256, 3)
__global__ void step_kernel(const __hip_bfloat16* __restrict__ C,
                            const float* __restrict__ theta_in,
                            float* __restrict__ theta_out,
                            const float* __restrict__ omega) {
    __shared__ float2 cs[NN];
    const int tid = threadIdx.x;
    const int b   = blockIdx.x >> 7;
    const int rb  = blockIdx.x & 127;
    const float* th_b = theta_in + b * NN;

    #pragma unroll
    for (int i = 0; i < 8; ++i) {
        int m = tid + 256 * i;          // coalesced
        float sv, cv;
        sincosf(th_b[m], &sv, &cv);
        cs[m] = make_float2(cv, sv);
    }
    __syncthreads();

    const int lane = tid & 63;
    const int wave = tid >> 6;

    float cc[32], ss[32];
    #pragma unroll
    for (int j = 0; j < 4; ++j) {
        #pragma unroll
        for (int i = 0; i < 8; ++i) {
            float2 v = cs[j * 512 + lane * 8 + i];
            cc[j * 8 + i] = v.x;
            ss[j * 8 + i] = v.y;
        }
    }

    const int row0 = rb * 16 + wave * 4;
    const __hip_bfloat16* Cb = C + ((size_t)b * NN + row0) * (size_t)NN + lane * 8;

    uint4 v[4][4];                       // all 16 loads in flight
    #pragma unroll
    for (int q = 0; q < 4; ++q)
        #pragma unroll
        for (int j = 0; j < 4; ++j)
            v[q][j] = *(const uint4*)(Cb + (size_t)q * NN + j * 512);

    float ac[4], as[4];
    #pragma unroll
    for (int q = 0; q < 4; ++q) {
        float a0 = 0.f, a1 = 0.f, s0 = 0.f, s1 = 0.f;
        #pragma unroll
        for (int j = 0; j < 4; ++j) {
            unsigned u[4] = {v[q][j].x, v[q][j].y, v[q][j].z, v[q][j].w};
            #pragma unroll
            for (int k = 0; k < 4; ++k) {
                float f0 = __uint_as_float(u[k] << 16);
                float f1 = __uint_as_float(u[k] & 0xffff0000u);
                int idx = j * 8 + 2 * k;
                a0 = fmaf(f0, cc[idx],     a0);
                s0 = fmaf(f0, ss[idx],     s0);
                a1 = fmaf(f1, cc[idx + 1], a1);
                s1 = fmaf(f1, ss[idx + 1], s1);
            }
        }
        ac[q] = a0 + a1;
        as[q] = s0 + s1;
    }

    #pragma unroll
    for (int q = 0; q < 4; ++q) {
        #pragma unroll
        for (int off = 32; off >= 1; off >>= 1) {
            ac[q] += __shfl_xor(ac[q], off, 64);
            as[q] += __shfl_xor(as[q], off, 64);
        }
    }

    if (lane < 4) {                      // butterfly left sum in every lane
        int q = lane;
        int n = row0 + q;
        float2 csn = cs[n];              // (cos, sin) of theta[n] — no recompute
        float sum  = csn.y * ac[q] - csn.x * as[q];
        float th   = th_b[n];
        float dth  = omega[n] + (1.0f / NN) * sum;
        theta_out[b * NN + n] = fmodf(th + DT_F * dth, TWO_PI_F);
    }
}

// ---------------- launch ----------------------------------------------------
extern "C" void kernel_launch(void* const* d_in, const int* in_sizes, int n_in,
                              void* d_out, int out_size, void* d_ws, size_t ws_size,
                              hipStream_t stream) {
    const float* theta0 = (const float*)d_in[0];
    const float* emb    = (const float*)d_in[1];
    const float* omega  = (const float*)d_in[2];
    float* out = (float*)d_out;

    char* ws = (char*)d_ws;
    __hip_bfloat16* C   = (__hip_bfloat16*)ws;                       // 64 MiB
    __hip_bfloat16* Ehi = (__hip_bfloat16*)(ws + 67108864);          // 4 MiB
    __hip_bfloat16* Elo = (__hip_bfloat16*)(ws + 71303168);          // 4 MiB
    float* tA = (float*)(ws + 75497472);                             // 64 KiB
    float* tB = (float*)(ws + 75563008);                             // 64 KiB

    split_kernel<<<(BB * NN * DD) / 256, 256, 0, stream>>>(emb, Ehi, Elo);

    dim3 g1(NN / 64, NN / 64, BB);
    coupling_kernel<<<g1, 256, 0, stream>>>(Ehi, Elo, C);

    const float* tin = theta0;
    for (int s = 0; s < NSTEPS; ++s) {
        float* tout = (s == NSTEPS - 1) ? out : ((s & 1) ? tB : tA);
        step_kernel<<<dim3(BB * (NN / 16)), 256, 0, stream>>>(C, tin, tout, omega);
        tin = tout;
    }
}

// Round 3
// 369.005 us; speedup vs baseline: 1.6445x; 1.0484x over previous
//
#include <hip/hip_runtime.h>
#include <hip/hip_bf16.h>

#define BB 8
#define NN 2048
#define DD 128
#define NSTEPS 16
#define DT_F 0.1f
#define TWO_PI_F 6.283185307179586f

typedef short short8 __attribute__((ext_vector_type(8)));
typedef float floatx4 __attribute__((ext_vector_type(4)));

// s_waitcnt vmcnt(N): vmcnt[3:0]=bits3:0, expcnt=0x7 (ignore), lgkmcnt=0xF (ignore)
#define WAITVM(N) __builtin_amdgcn_s_waitcnt(0xF70 | (N))

// ---------------- K0: split fp32 embeddings into bf16 hi/lo ----------------
__global__ void split_kernel(const float* __restrict__ e,
                             __hip_bfloat16* __restrict__ hi,
                             __hip_bfloat16* __restrict__ lo) {
    int i = blockIdx.x * 256 + threadIdx.x;
    float x = e[i];
    __hip_bfloat16 h = __float2bfloat16(x);
    hi[i] = h;
    lo[i] = __float2bfloat16(x - __bfloat162float(h));
}

// ---------------- K1: coupling matrix via bf16 MFMA (hi/lo split) ----------
// exp(-acosh(x)) = 1/(x + sqrt(x^2-1)); /1.000001 tau factor <=1e-5 rel.
#define LDP 136

__launch_bounds__(256, 2)
__global__ void coupling_kernel(const __hip_bfloat16* __restrict__ Ehi,
                                const __hip_bfloat16* __restrict__ Elo,
                                __hip_bfloat16* __restrict__ C) {
    __shared__ __hip_bfloat16 Ah[64 * LDP];
    __shared__ __hip_bfloat16 Al[64 * LDP];
    __shared__ __hip_bfloat16 Bh[64 * LDP];
    __shared__ __hip_bfloat16 Bl[64 * LDP];

    const int b  = blockIdx.z;
    const int n0 = blockIdx.y * 64;
    const int m0 = blockIdx.x * 64;
    const int tid = threadIdx.x;

    const __hip_bfloat16* aHsrc = Ehi + ((size_t)b * NN + n0) * DD;
    const __hip_bfloat16* aLsrc = Elo + ((size_t)b * NN + n0) * DD;
    const __hip_bfloat16* bHsrc = Ehi + ((size_t)b * NN + m0) * DD;
    const __hip_bfloat16* bLsrc = Elo + ((size_t)b * NN + m0) * DD;

    #pragma unroll
    for (int i = 0; i < 4; ++i) {
        int c   = tid + 256 * i;
        int row = c >> 4;
        int col = (c & 15) * 8;
        *(uint4*)(Ah + row * LDP + col) = *(const uint4*)(aHsrc + row * DD + col);
        *(uint4*)(Al + row * LDP + col) = *(const uint4*)(aLsrc + row * DD + col);
        *(uint4*)(Bh + row * LDP + col) = *(const uint4*)(bHsrc + row * DD + col);
        *(uint4*)(Bl + row * LDP + col) = *(const uint4*)(bLsrc + row * DD + col);
    }
    __syncthreads();

    const int wave = tid >> 6;
    const int lane = tid & 63;
    const int l16  = lane & 15;
    const int quad = lane >> 4;

    floatx4 acc[4] = {floatx4{0,0,0,0}, floatx4{0,0,0,0},
                      floatx4{0,0,0,0}, floatx4{0,0,0,0}};

    const int arow = wave * 16 + l16;
    #pragma unroll
    for (int kt = 0; kt < 4; ++kt) {
        const int ko = kt * 32 + quad * 8;
        short8 ah = *(const short8*)(Ah + arow * LDP + ko);
        short8 al = *(const short8*)(Al + arow * LDP + ko);
        #pragma unroll
        for (int c = 0; c < 4; ++c) {
            const int brow = c * 16 + l16;
            short8 bh = *(const short8*)(Bh + brow * LDP + ko);
            short8 bl = *(const short8*)(Bl + brow * LDP + ko);
            acc[c] = __builtin_amdgcn_mfma_f32_16x16x32_bf16(ah, bh, acc[c], 0, 0, 0);
            acc[c] = __builtin_amdgcn_mfma_f32_16x16x32_bf16(ah, bl, acc[c], 0, 0, 0);
            acc[c] = __builtin_amdgcn_mfma_f32_16x16x32_bf16(al, bh, acc[c], 0, 0, 0);
        }
    }

    float tn2[4];
    #pragma unroll
    for (int i = 0; i < 4; ++i) {
        int r = wave * 16 + quad * 4 + i;
        tn2[i] = 2.0f * (__bfloat162float(Ah[r * LDP]) + __bfloat162float(Al[r * LDP]));
    }
    #pragma unroll
    for (int c = 0; c < 4; ++c) {
        int br = c * 16 + l16;
        float tm = __bfloat162float(Bh[br * LDP]) + __bfloat162float(Bl[br * LDP]);
        size_t base = ((size_t)b * NN + n0 + wave * 16 + quad * 4) * (size_t)NN
                      + m0 + c * 16 + l16;
        #pragma unroll
        for (int i = 0; i < 4; ++i) {
            float g   = acc[c][i];
            float arg = fmaxf(fmaf(tn2[i], tm, -g), 1.0f + 1e-7f);
            float s   = sqrtf(fmaf(arg, arg, -1.0f));
            float cp  = __builtin_amdgcn_rcpf(arg + s);
            C[base + (size_t)i * NN] = __float2bfloat16(fminf(cp, 1.0f));
        }
    }
}

// ---------------- K2: one Kuramoto step (async-DMA pipelined) --------------
// 512 blocks (2/CU), 4 waves/block, 8 rows/wave. Each wave streams its C rows
// through a private 3-row LDS ring via global_load_lds(16B); fine-grained
// s_waitcnt vmcnt(N) only — NO barriers in the row loop (per-wave ownership).

__device__ __forceinline__ void issue_row(const __hip_bfloat16* gsrc,
                                          __hip_bfloat16* lds_row) {
    #pragma unroll
    for (int k = 0; k < 4; ++k) {
        __builtin_amdgcn_global_load_lds(
            (const __attribute__((address_space(1))) unsigned int*)(gsrc + k * 512),
            (__attribute__((address_space(3))) unsigned int*)(lds_row + k * 512),
            16, 0, 0);
    }
}

__device__ __forceinline__ void consume_row(const __hip_bfloat16* lrow, int lane,
                                            const float (&cc)[32], const float (&ss)[32],
                                            float& outc, float& outs) {
    float a0 = 0.f, a1 = 0.f, s0 = 0.f, s1 = 0.f;
    #pragma unroll
    for (int j = 0; j < 4; ++j) {
        uint4 v = *(const uint4*)(lrow + j * 512 + lane * 8);   // ds_read_b128
        unsigned u[4] = {v.x, v.y, v.z, v.w};
        #pragma unroll
        for (int k = 0; k < 4; ++k) {
            float f0 = __uint_as_float(u[k] << 16);
            float f1 = __uint_as_float(u[k] & 0xffff0000u);
            int idx = j * 8 + 2 * k;
            a0 = fmaf(f0, cc[idx],     a0);
            s0 = fmaf(f0, ss[idx],     s0);
            a1 = fmaf(f1, cc[idx + 1], a1);
            s1 = fmaf(f1, ss[idx + 1], s1);
        }
    }
    outc = a0 + a1;
    outs = s0 + s1;
}

__launch_bounds__(256, 2)
__global__ void step_kernel(const __hip_bfloat16* __restrict__ C,
                            const float* __restrict__ theta_in,
                            float* __restrict__ theta_out,
                            const float* __restrict__ omega) {
    __shared__ float2 cs[NN];                                     // 16 KB
    __shared__ __align__(16) __hip_bfloat16 cbuf[4][3][2048];     // 48 KB ring

    const int tid = threadIdx.x;
    const int b   = blockIdx.x >> 6;        // 64 row-groups of 32 per batch
    const int rg  = blockIdx.x & 63;
    const float* th_b = theta_in + b * NN;

    const int lane = tid & 63;
    const int wave = tid >> 6;
    const int row0 = rg * 32 + wave * 8;

    const size_t NNs = NN;
    const __hip_bfloat16* Cw = C + ((size_t)b * NN + row0) * NNs + lane * 8;
    __hip_bfloat16* lb = &cbuf[wave][0][0];

    // build cs table (cos,sin of all theta)
    #pragma unroll
    for (int i = 0; i < 8; ++i) {
        int m = tid + 256 * i;
        float sv, cv;
        __sincosf(th_b[m], &sv, &cv);
        cs[m] = make_float2(cv, sv);
    }

    // prologue DMA: rows 0..2 (the barrier below drains them into LDS)
    issue_row(Cw,            lb);
    issue_row(Cw + NNs,      lb + 2048);
    issue_row(Cw + 2 * NNs,  lb + 4096);

    __syncthreads();   // cs ready; also vmcnt(0) => rows 0-2 landed

    float cc[32], ss[32];
    #pragma unroll
    for (int j = 0; j < 4; ++j) {
        #pragma unroll
        for (int i = 0; i < 8; ++i) {
            float2 v = cs[j * 512 + lane * 8 + i];
            cc[j * 8 + i] = v.x;
            ss[j * 8 + i] = v.y;
        }
    }

    float sumc[8], sums[8];
    // steady-state: consume r, issue r+3 into freed buffer, never vmcnt(0)
    consume_row(lb,        lane, cc, ss, sumc[0], sums[0]);
    issue_row(Cw + 3 * NNs, lb);                                  // 4 out
    consume_row(lb + 2048, lane, cc, ss, sumc[1], sums[1]);
    issue_row(Cw + 4 * NNs, lb + 2048);                           // 8 out
    consume_row(lb + 4096, lane, cc, ss, sumc[2], sums[2]);
    issue_row(Cw + 5 * NNs, lb + 4096);                           // 12 out
    WAITVM(8);   // row 3 landed
    consume_row(lb,        lane, cc, ss, sumc[3], sums[3]);
    issue_row(Cw + 6 * NNs, lb);                                  // 12 out
    WAITVM(8);   // row 4 landed
    consume_row(lb + 2048, lane, cc, ss, sumc[4], sums[4]);
    issue_row(Cw + 7 * NNs, lb + 2048);                           // 12 out
    WAITVM(8);   // row 5 landed
    consume_row(lb + 4096, lane, cc, ss, sumc[5], sums[5]);
    WAITVM(4);   // row 6 landed
    consume_row(lb,        lane, cc, ss, sumc[6], sums[6]);
    WAITVM(0);   // row 7 landed
    consume_row(lb + 2048, lane, cc, ss, sumc[7], sums[7]);

    #pragma unroll
    for (int r = 0; r < 8; ++r) {
        #pragma unroll
        for (int off = 32; off >= 1; off >>= 1) {
            sumc[r] += __shfl_xor(sumc[r], off, 64);
            sums[r] += __shfl_xor(sums[r], off, 64);
        }
    }

    #pragma unroll
    for (int r = 0; r < 8; ++r) {
        if (lane == r) {
            int n = row0 + r;
            float2 csn = cs[n];
            float sum  = csn.y * sumc[r] - csn.x * sums[r];
            float th   = th_b[n];
            float dth  = omega[n] + (1.0f / NN) * sum;
            theta_out[b * NN + n] = fmodf(th + DT_F * dth, TWO_PI_F);
        }
    }
}

// ---------------- launch ----------------------------------------------------
extern "C" void kernel_launch(void* const* d_in, const int* in_sizes, int n_in,
                              void* d_out, int out_size, void* d_ws, size_t ws_size,
                              hipStream_t stream) {
    const float* theta0 = (const float*)d_in[0];
    const float* emb    = (const float*)d_in[1];
    const float* omega  = (const float*)d_in[2];
    float* out = (float*)d_out;

    char* ws = (char*)d_ws;
    __hip_bfloat16* C   = (__hip_bfloat16*)ws;                       // 64 MiB
    __hip_bfloat16* Ehi = (__hip_bfloat16*)(ws + 67108864);          // 4 MiB
    __hip_bfloat16* Elo = (__hip_bfloat16*)(ws + 71303168);          // 4 MiB
    float* tA = (float*)(ws + 75497472);                             // 64 KiB
    float* tB = (float*)(ws + 75563008);                             // 64 KiB

    split_kernel<<<(BB * NN * DD) / 256, 256, 0, stream>>>(emb, Ehi, Elo);

    dim3 g1(NN / 64, NN / 64, BB);
    coupling_kernel<<<g1, 256, 0, stream>>>(Ehi, Elo, C);

    const float* tin = theta0;
    for (int s = 0; s < NSTEPS; ++s) {
        float* tout = (s == NSTEPS - 1) ? out : ((s & 1) ? tB : tA);
        step_kernel<<<dim3(BB * (NN / 32)), 256, 0, stream>>>(C, tin, tout, omega);
        tin = tout;
    }
}